// Round 5
// baseline (3712.434 us; speedup 1.0000x reference)
//
#include <hip/hip_runtime.h>
#include <hip/hip_bf16.h>

#define N_NODES 32000
#define FIN     128
#define E_EDGES 512000
#define EF_EDGES 544000
#define HC      64
#define NGRAPH  32
#define PROJ    8
#define OUT_DIM 256
#define NBLK    1024

// fp32 -> bf16 (RTNE) and back
static __device__ inline unsigned short f2bf(float f) {
  unsigned int x = __float_as_uint(f);
  unsigned int r = (x + 0x7fffu + ((x >> 16) & 1u)) >> 16;
  return (unsigned short)r;
}
static __device__ inline float bf2f(unsigned short u) {
  return __uint_as_float((unsigned int)u << 16);
}

struct Params {
  const float *x, *edge_attr, *W0, *a_s0, *a_d0, *W_e0, *a_e0, *b0;
  const float *Wg, *a_sg, *a_dg, *W_eg, *a_eg, *bg;
  const float *Wp, *bp, *Wo, *bo;
  const int* ei;
  int *deg, *offs, *nxt, *bsum, *boffs;
  int *csr_src, *csr_eid, *csr_pos;
  float *loop_attr, *lge;
  unsigned short* xlb;
  float *al_s, *al_d, *hA, *hB, *pbuf, *part, *out;
  int* bar;
};

union Smem {
  struct { float sW[64][64]; float sA[64][65]; } t;   // 33024 B (max)
  float sp[NGRAPH][250];                               // 32000 B
  float Me[3][16][4];                                  // 768 B
  int wsum[4];
};

// monotonic-counter grid barrier; bar zeroed by zbar_kernel each launch.
// Correct for any #generations: target = gen*NBLK, counter only grows.
__device__ __forceinline__ void gbar(int* bar, int target) {
  __syncthreads();
  if (threadIdx.x == 0) {
    __threadfence();  // publish this block's writes (device scope)
    __hip_atomic_fetch_add(bar, 1, __ATOMIC_RELEASE, __HIP_MEMORY_SCOPE_AGENT);
    while (__hip_atomic_load(bar, __ATOMIC_ACQUIRE, __HIP_MEMORY_SCOPE_AGENT) < target)
      __builtin_amdgcn_s_sleep(16);
  }
  __syncthreads();
  __threadfence();    // invalidate L1 so post-barrier loads see remote writes
}

__device__ __forceinline__ void transform_tile(
    int tile, int K, const float* __restrict__ A, const float* __restrict__ W,
    const float* __restrict__ a_s, const float* __restrict__ a_d,
    unsigned short* __restrict__ xlb, float* __restrict__ al_s,
    float* __restrict__ al_d, Smem& sm) {
  int tid = threadIdx.x;
  int row0 = tile * 64;
  int tx = tid & 15, ty = tid >> 4;
  int c0 = tx * 4, r0 = ty * 4;
  float acc[4][4] = {};
  for (int kc = 0; kc < K; kc += 64) {
    for (int i = tid; i < 1024; i += 256) {
      int kk = i >> 4, c4 = (i & 15) * 4;
      *(float4*)&sm.t.sW[kk][c4] = *(const float4*)&W[(size_t)(kc + kk) * HC + c4];
    }
    for (int i = tid; i < 1024; i += 256) {
      int r = i >> 4, k4 = (i & 15) * 4;
      float4 v = *(const float4*)&A[(size_t)(row0 + r) * K + kc + k4];
      sm.t.sA[r][k4 + 0] = v.x; sm.t.sA[r][k4 + 1] = v.y;
      sm.t.sA[r][k4 + 2] = v.z; sm.t.sA[r][k4 + 3] = v.w;
    }
    __syncthreads();
#pragma unroll 8
    for (int kk = 0; kk < 64; ++kk) {
      float4 w = *(float4*)&sm.t.sW[kk][c0];
      float a0 = sm.t.sA[r0 + 0][kk];
      float a1 = sm.t.sA[r0 + 1][kk];
      float a2 = sm.t.sA[r0 + 2][kk];
      float a3 = sm.t.sA[r0 + 3][kk];
      acc[0][0] = fmaf(a0, w.x, acc[0][0]); acc[0][1] = fmaf(a0, w.y, acc[0][1]);
      acc[0][2] = fmaf(a0, w.z, acc[0][2]); acc[0][3] = fmaf(a0, w.w, acc[0][3]);
      acc[1][0] = fmaf(a1, w.x, acc[1][0]); acc[1][1] = fmaf(a1, w.y, acc[1][1]);
      acc[1][2] = fmaf(a1, w.z, acc[1][2]); acc[1][3] = fmaf(a1, w.w, acc[1][3]);
      acc[2][0] = fmaf(a2, w.x, acc[2][0]); acc[2][1] = fmaf(a2, w.y, acc[2][1]);
      acc[2][2] = fmaf(a2, w.z, acc[2][2]); acc[2][3] = fmaf(a2, w.w, acc[2][3]);
      acc[3][0] = fmaf(a3, w.x, acc[3][0]); acc[3][1] = fmaf(a3, w.y, acc[3][1]);
      acc[3][2] = fmaf(a3, w.z, acc[3][2]); acc[3][3] = fmaf(a3, w.w, acc[3][3]);
    }
    __syncthreads();
  }
  float asv[4], adv[4];
#pragma unroll
  for (int j = 0; j < 4; ++j) { asv[j] = a_s[c0 + j]; adv[j] = a_d[c0 + j]; }
  int hd = tx >> 2;
#pragma unroll
  for (int i = 0; i < 4; ++i) {
    int r = row0 + r0 + i;
    ushort4 u = make_ushort4(f2bf(acc[i][0]), f2bf(acc[i][1]),
                             f2bf(acc[i][2]), f2bf(acc[i][3]));
    *(ushort4*)&xlb[(size_t)r * HC + c0] = u;
    float ps = acc[i][0] * asv[0] + acc[i][1] * asv[1] + acc[i][2] * asv[2] + acc[i][3] * asv[3];
    float pd = acc[i][0] * adv[0] + acc[i][1] * adv[1] + acc[i][2] * adv[2] + acc[i][3] * adv[3];
    ps += __shfl_xor(ps, 1); ps += __shfl_xor(ps, 2);
    pd += __shfl_xor(pd, 1); pd += __shfl_xor(pd, 2);
    if ((tx & 3) == 0) {
      al_s[(size_t)r * 4 + hd] = ps;
      al_d[(size_t)r * 4 + hd] = pd;
    }
  }
}

// online softmax + aggregation for one dst node (one wave), al_s folded in
__device__ __forceinline__ void gather_node(
    int n, int lane, const int* __restrict__ offs, const int* __restrict__ csr_src,
    const float* __restrict__ lg, const unsigned short* __restrict__ xlb,
    const float* __restrict__ al_s, const float* __restrict__ al_d,
    const float* __restrict__ bias, const float* __restrict__ Wp,
    const float* __restrict__ bp, float* __restrict__ outp, int fuse) {
  int hd = lane >> 4;
  int beg = offs[n], end = offs[n + 1];
  float ald = al_d[(size_t)n * 4 + hd];
  float m = -1e30f, denom = 0.f, acc = 0.f;
  int i = beg;
  for (; i + 4 <= end; i += 4) {
    int s0 = csr_src[i + 0];
    int s1 = csr_src[i + 1];
    int s2 = csr_src[i + 2];
    int s3 = csr_src[i + 3];
    float l0 = lg[(size_t)(i + 0) * 4 + hd] + al_s[(size_t)s0 * 4 + hd] + ald;
    float l1 = lg[(size_t)(i + 1) * 4 + hd] + al_s[(size_t)s1 * 4 + hd] + ald;
    float l2 = lg[(size_t)(i + 2) * 4 + hd] + al_s[(size_t)s2 * 4 + hd] + ald;
    float l3 = lg[(size_t)(i + 3) * 4 + hd] + al_s[(size_t)s3 * 4 + hd] + ald;
    l0 = (l0 > 0.f) ? l0 : 0.2f * l0;
    l1 = (l1 > 0.f) ? l1 : 0.2f * l1;
    l2 = (l2 > 0.f) ? l2 : 0.2f * l2;
    l3 = (l3 > 0.f) ? l3 : 0.2f * l3;
    unsigned short x0 = xlb[(size_t)s0 * HC + lane];
    unsigned short x1 = xlb[(size_t)s1 * HC + lane];
    unsigned short x2 = xlb[(size_t)s2 * HC + lane];
    unsigned short x3 = xlb[(size_t)s3 * HC + lane];
    float mx = fmaxf(fmaxf(fmaxf(l0, l1), fmaxf(l2, l3)), m);
    float sc = __expf(m - mx);
    float p0 = __expf(l0 - mx);
    float p1 = __expf(l1 - mx);
    float p2 = __expf(l2 - mx);
    float p3 = __expf(l3 - mx);
    denom = denom * sc + ((p0 + p1) + (p2 + p3));
    acc = acc * sc + p0 * bf2f(x0) + p1 * bf2f(x1) + p2 * bf2f(x2) + p3 * bf2f(x3);
    m = mx;
  }
  for (; i < end; ++i) {
    int s = csr_src[i];
    float l = lg[(size_t)i * 4 + hd] + al_s[(size_t)s * 4 + hd] + ald;
    l = (l > 0.f) ? l : 0.2f * l;
    float mx = fmaxf(m, l);
    float sc = __expf(m - mx);
    float pp = __expf(l - mx);
    denom = denom * sc + pp;
    acc = acc * sc + pp * bf2f(xlb[(size_t)s * HC + lane]);
    m = mx;
  }
  float hv = fmaxf(acc / denom + bias[lane], 0.f);
  if (!fuse) {
    outp[(size_t)n * HC + lane] = hv;
  } else {
    float pj[8];
#pragma unroll
    for (int j = 0; j < 8; ++j) pj[j] = hv * Wp[lane * PROJ + j];
#pragma unroll
    for (int off = 1; off < 64; off <<= 1) {
#pragma unroll
      for (int j = 0; j < 8; ++j) pj[j] += __shfl_xor(pj[j], off);
    }
    if (lane < 8) {
      float v = pj[0];
      v = (lane == 1) ? pj[1] : v;
      v = (lane == 2) ? pj[2] : v;
      v = (lane == 3) ? pj[3] : v;
      v = (lane == 4) ? pj[4] : v;
      v = (lane == 5) ? pj[5] : v;
      v = (lane == 6) ? pj[6] : v;
      v = (lane == 7) ? pj[7] : v;
      outp[(size_t)n * PROJ + lane] = fmaxf(v + bp[lane], 0.f);
    }
  }
}

__device__ __forceinline__ void compute_Me(const Params& p, Smem& sm) {
  int tid = threadIdx.x;
  if (tid < 192) {
    int l = tid >> 6, r6 = tid & 63, d = r6 >> 2, h = r6 & 3;
    const float* We = (l == 0) ? p.W_e0 : p.W_eg + (size_t)(l - 1) * 16 * HC;
    const float* ae = (l == 0) ? p.a_e0 : p.a_eg + (size_t)(l - 1) * 64;
    float s = 0.f;
#pragma unroll
    for (int c = 0; c < 16; ++c) s += We[d * HC + h * 16 + c] * ae[h * 16 + c];
    sm.Me[l][d][h] = s;
  }
  __syncthreads();
}

__device__ __forceinline__ void elogit_write(const Params& p, Smem& sm,
                                             const float* av16, int pos) {
#pragma unroll
  for (int l = 0; l < 3; ++l) {
    float r0 = 0.f, r1 = 0.f, r2 = 0.f, r3 = 0.f;
#pragma unroll
    for (int d = 0; d < 16; ++d) {
      float a = av16[d];
      r0 = fmaf(a, sm.Me[l][d][0], r0);
      r1 = fmaf(a, sm.Me[l][d][1], r1);
      r2 = fmaf(a, sm.Me[l][d][2], r2);
      r3 = fmaf(a, sm.Me[l][d][3], r3);
    }
    *(float4*)&p.lge[((size_t)l * EF_EDGES + pos) * 4] = make_float4(r0, r1, r2, r3);
  }
}

__global__ void zbar_kernel(int* bar) {
  if (threadIdx.x == 0) bar[0] = 0;
}

__global__ __launch_bounds__(256, 4) void mega_kernel(Params p) {
  __shared__ Smem sm;
  const int tid = threadIdx.x;
  const int bid = blockIdx.x;
  const int lane = tid & 63;
  const int wv = tid >> 6;
  int gen = 0;

  // ---- A: zero deg (125 vbs) ----
  for (int vb = bid; vb < N_NODES / 256; vb += NBLK) p.deg[vb * 256 + tid] = 0;
  gbar(p.bar, ++gen * NBLK);

  // ---- B: degree count (2000 vbs) ----
  for (int vb = bid; vb < E_EDGES / 256; vb += NBLK)
    atomicAdd(&p.deg[p.ei[E_EDGES + vb * 256 + tid]], 1);
  gbar(p.bar, ++gen * NBLK);

  // ---- C: scan1 (125 vbs) ----
  for (int vb = bid; vb < N_NODES / 256; vb += NBLK) {
    int idx = vb * 256 + tid;
    int v = p.deg[idx] + 1;   // +1 self-loop
    int s = v;
#pragma unroll
    for (int off = 1; off < 64; off <<= 1) {
      int t = __shfl_up(s, off);
      if (lane >= off) s += t;
    }
    if (lane == 63) sm.wsum[wv] = s;
    __syncthreads();
    int add = 0;
#pragma unroll
    for (int i = 0; i < 4; ++i) add += (i < wv) ? sm.wsum[i] : 0;
    int incl = s + add;
    p.offs[idx] = incl - v;
    if (tid == 255) p.bsum[vb] = incl;
    __syncthreads();
  }
  gbar(p.bar, ++gen * NBLK);

  // ---- D: scan2 (block 0 only) ----
  if (bid == 0) {
    int v = (tid < 125) ? p.bsum[tid] : 0;
    int s = v;
#pragma unroll
    for (int off = 1; off < 64; off <<= 1) {
      int t = __shfl_up(s, off);
      if (lane >= off) s += t;
    }
    if (lane == 63) sm.wsum[wv] = s;
    __syncthreads();
    int incl = s + ((wv == 1) ? sm.wsum[0] : 0);
    if (tid < 125) p.boffs[tid] = incl - v;
    if (tid == 127) p.offs[N_NODES] = incl;   // grand total = EF_EDGES
  }
  gbar(p.bar, ++gen * NBLK);

  // ---- E: scan3 (125 vbs) ----
  for (int vb = bid; vb < N_NODES / 256; vb += NBLK) {
    int idx = vb * 256 + tid;
    int o = p.offs[idx] + p.boffs[vb];
    p.offs[idx] = o;
    p.nxt[idx] = o;
  }
  gbar(p.bar, ++gen * NBLK);

  // ---- F: CSR fill (2125 vbs) + transform layer0 (500 vbs) ----
  for (int vb = bid; vb < EF_EDGES / 256 + 500; vb += NBLK) {
    if (vb < EF_EDGES / 256) {
      int e = vb * 256 + tid;
      int s, d;
      if (e < E_EDGES) { s = p.ei[e]; d = p.ei[E_EDGES + e]; }
      else             { s = e - E_EDGES; d = s; }
      int pos = atomicAdd(&p.nxt[d], 1);
      p.csr_src[pos] = s;
      p.csr_eid[pos] = e;
      p.csr_pos[e] = pos;
    } else {
      transform_tile(vb - EF_EDGES / 256, FIN, p.x, p.W0, p.a_s0, p.a_d0,
                     p.xlb, p.al_s, p.al_d, sm);
    }
  }
  gbar(p.bar, ++gen * NBLK);

  // ---- G: loop_attr (8000 vbs) + edge logits for real edges (2000 vbs) ----
  compute_Me(p, sm);
  for (int vb = bid; vb < 10000; vb += NBLK) {
    if (vb < 8000) {
      int n = vb * 4 + wv;
      int k = lane & 15, g = lane >> 4;
      int beg = p.offs[n], end = p.offs[n + 1];
      float s = 0.f;
      for (int i = beg + g; i < end; i += 4) {
        int e = p.csr_eid[i];
        if (e < E_EDGES) s += p.edge_attr[(size_t)e * 16 + k];
      }
      s += __shfl_xor(s, 16);
      s += __shfl_xor(s, 32);
      int degv = end - beg - 1;
      if (g == 0) p.loop_attr[(size_t)n * 16 + k] = s / fmaxf((float)degv, 1.f);
    } else {
      int e = (vb - 8000) * 256 + tid;
      float av[16];
      *(float4*)&av[0]  = *(const float4*)&p.edge_attr[(size_t)e * 16 + 0];
      *(float4*)&av[4]  = *(const float4*)&p.edge_attr[(size_t)e * 16 + 4];
      *(float4*)&av[8]  = *(const float4*)&p.edge_attr[(size_t)e * 16 + 8];
      *(float4*)&av[12] = *(const float4*)&p.edge_attr[(size_t)e * 16 + 12];
      elogit_write(p, sm, av, p.csr_pos[e]);
    }
  }
  gbar(p.bar, ++gen * NBLK);

  // ---- H: edge logits for self-loops (125 vbs) ----
  compute_Me(p, sm);
  for (int vb = bid; vb < N_NODES / 256; vb += NBLK) {
    int n = vb * 256 + tid;
    float av[16];
    *(float4*)&av[0]  = *(const float4*)&p.loop_attr[(size_t)n * 16 + 0];
    *(float4*)&av[4]  = *(const float4*)&p.loop_attr[(size_t)n * 16 + 4];
    *(float4*)&av[8]  = *(const float4*)&p.loop_attr[(size_t)n * 16 + 8];
    *(float4*)&av[12] = *(const float4*)&p.loop_attr[(size_t)n * 16 + 12];
    elogit_write(p, sm, av, p.csr_pos[E_EDGES + n]);
  }
  gbar(p.bar, ++gen * NBLK);

  // ---- I: gather layer0 -> hA ----
  for (int vb = bid; vb < N_NODES / 4; vb += NBLK)
    gather_node(vb * 4 + wv, lane, p.offs, p.csr_src, p.lge, p.xlb,
                p.al_s, p.al_d, p.b0, p.Wp, p.bp, p.hA, 0);
  gbar(p.bar, ++gen * NBLK);

  // ---- J: transform layer1 (hA) ----
  for (int vb = bid; vb < 500; vb += NBLK)
    transform_tile(vb, HC, p.hA, p.Wg, p.a_sg, p.a_dg, p.xlb, p.al_s, p.al_d, sm);
  gbar(p.bar, ++gen * NBLK);

  // ---- K: gather layer1 -> hB ----
  for (int vb = bid; vb < N_NODES / 4; vb += NBLK)
    gather_node(vb * 4 + wv, lane, p.offs, p.csr_src, p.lge + (size_t)EF_EDGES * 4,
                p.xlb, p.al_s, p.al_d, p.bg, p.Wp, p.bp, p.hB, 0);
  gbar(p.bar, ++gen * NBLK);

  // ---- L: transform layer2 (hB) ----
  for (int vb = bid; vb < 500; vb += NBLK)
    transform_tile(vb, HC, p.hB, p.Wg + HC * HC, p.a_sg + 64, p.a_dg + 64,
                   p.xlb, p.al_s, p.al_d, sm);
  gbar(p.bar, ++gen * NBLK);

  // ---- M: gather layer2 + fused proj -> pbuf ----
  for (int vb = bid; vb < N_NODES / 4; vb += NBLK)
    gather_node(vb * 4 + wv, lane, p.offs, p.csr_src, p.lge + (size_t)2 * EF_EDGES * 4,
                p.xlb, p.al_s, p.al_d, p.bg + 64, p.Wp, p.bp, p.pbuf, 1);
  gbar(p.bar, ++gen * NBLK);

  // ---- N: fc1 (128 vbs) ----
  for (int vb = bid; vb < 128; vb += NBLK) {
    int kc = vb >> 2, ct = vb & 3;
    for (int idx = tid; idx < NGRAPH * 250; idx += 256) {
      int g = idx / 250, kk = idx % 250;
      sm.sp[g][kk] = p.pbuf[(size_t)g * 8000 + kc * 250 + kk];
    }
    __syncthreads();
    int c = ct * 64 + lane;
    float acc[NGRAPH] = {};
    for (int kk = wv; kk < 250; kk += 4) {
      float w = p.Wo[(size_t)(kc * 250 + kk) * OUT_DIM + c];
#pragma unroll
      for (int g = 0; g < NGRAPH; ++g) acc[g] = fmaf(sm.sp[g][kk], w, acc[g]);
    }
    int ch = kc * 4 + wv;
#pragma unroll
    for (int g = 0; g < NGRAPH; ++g)
      p.part[((size_t)ch * NGRAPH + g) * OUT_DIM + c] = acc[g];
  }
  gbar(p.bar, ++gen * NBLK);

  // ---- O: fc2 (32 vbs) ----
  for (int vb = bid; vb < 32; vb += NBLK) {
    int i = vb * 256 + tid;
    int g = i >> 8, c = i & 255;
    float s = p.bo[c];
    for (int ch = 0; ch < 128; ++ch)
      s += p.part[((size_t)ch * NGRAPH + g) * OUT_DIM + c];
    p.out[i] = s;
  }
}

extern "C" void kernel_launch(void* const* d_in, const int* in_sizes, int n_in,
                              void* d_out, int out_size, void* d_ws, size_t ws_size,
                              hipStream_t stream) {
  char* base = (char*)d_ws;
  size_t off = 0;
  auto alloc = [&](size_t bytes) -> void* {
    void* ptr = base + off;
    off = (off + bytes + 255) & ~(size_t)255;
    return ptr;
  };

  Params p;
  p.x         = (const float*)d_in[0];
  p.edge_attr = (const float*)d_in[1];
  p.W0        = (const float*)d_in[2];
  p.a_s0      = (const float*)d_in[3];
  p.a_d0      = (const float*)d_in[4];
  p.W_e0      = (const float*)d_in[5];
  p.a_e0      = (const float*)d_in[6];
  p.b0        = (const float*)d_in[7];
  p.Wg        = (const float*)d_in[8];
  p.a_sg      = (const float*)d_in[9];
  p.a_dg      = (const float*)d_in[10];
  p.W_eg      = (const float*)d_in[11];
  p.a_eg      = (const float*)d_in[12];
  p.bg        = (const float*)d_in[13];
  p.Wp        = (const float*)d_in[14];
  p.bp        = (const float*)d_in[15];
  p.Wo        = (const float*)d_in[16];
  p.bo        = (const float*)d_in[17];
  p.ei        = (const int*)d_in[18];

  p.deg       = (int*)alloc((size_t)N_NODES * 4);
  p.offs      = (int*)alloc((size_t)(N_NODES + 1) * 4);
  p.nxt       = (int*)alloc((size_t)N_NODES * 4);
  p.bsum      = (int*)alloc(128 * 4);
  p.boffs     = (int*)alloc(128 * 4);
  p.csr_src   = (int*)alloc((size_t)EF_EDGES * 4);
  p.csr_eid   = (int*)alloc((size_t)EF_EDGES * 4);
  p.csr_pos   = (int*)alloc((size_t)EF_EDGES * 4);
  p.loop_attr = (float*)alloc((size_t)N_NODES * 16 * 4);
  p.lge       = (float*)alloc((size_t)3 * EF_EDGES * 4 * 4);
  p.xlb       = (unsigned short*)alloc((size_t)N_NODES * HC * 2);
  p.al_s      = (float*)alloc((size_t)N_NODES * 4 * 4);
  p.al_d      = (float*)alloc((size_t)N_NODES * 4 * 4);
  p.hA        = (float*)alloc((size_t)N_NODES * HC * 4);
  p.hB        = (float*)alloc((size_t)N_NODES * HC * 4);
  p.pbuf      = (float*)alloc((size_t)N_NODES * PROJ * 4);
  p.part      = (float*)alloc((size_t)128 * NGRAPH * OUT_DIM * 4);
  p.bar       = (int*)alloc(256);
  p.out       = (float*)d_out;

  zbar_kernel<<<1, 64, 0, stream>>>(p.bar);
  mega_kernel<<<NBLK, 256, 0, stream>>>(p);
}

// Round 7
// 320.282 us; speedup vs baseline: 11.5911x; 11.5911x over previous
//
#include <hip/hip_runtime.h>
#include <hip/hip_bf16.h>
#include <hip/hip_fp16.h>

#define N_NODES 32000
#define FIN     128
#define E_EDGES 512000
#define EF_EDGES 544000
#define HC      64
#define NGRAPH  32
#define PROJ    8
#define OUT_DIM 256

// fp32 -> bf16 (RTNE) and back
static __device__ inline unsigned short f2bf(float f) {
  unsigned int x = __float_as_uint(f);
  unsigned int r = (x + 0x7fffu + ((x >> 16) & 1u)) >> 16;
  return (unsigned short)r;
}
static __device__ inline float bf2f(unsigned short u) {
  return __uint_as_float((unsigned int)u << 16);
}
// fp32 <-> fp16
static __device__ inline unsigned short f2h(float f) {
  return __half_as_ushort(__float2half(f));
}
static __device__ inline float h2f(unsigned short u) {
  return __half2float(__ushort_as_half(u));
}

// ---------------- zero deg ----------------
__global__ __launch_bounds__(256) void zero_kernel(int* __restrict__ deg) {
  deg[blockIdx.x * 256 + threadIdx.x] = 0;
}

// ---------------- degree count (int atomics) ----------------
__global__ __launch_bounds__(256) void deg_kernel(const int* __restrict__ ei,
                                                  int* __restrict__ deg) {
  int e = blockIdx.x * 256 + threadIdx.x;   // grid exactly E/256
  atomicAdd(&deg[ei[E_EDGES + e]], 1);
}

// ---------------- scan phase 1: per-block exclusive scan + block sums ----------------
__global__ __launch_bounds__(256) void scan1_kernel(const int* __restrict__ deg,
                                                    int* __restrict__ offs,
                                                    int* __restrict__ bsum) {
  int idx = blockIdx.x * 256 + threadIdx.x;   // grid exactly 125
  int lane = threadIdx.x & 63;
  int w = threadIdx.x >> 6;
  int v = deg[idx] + 1;   // +1 self-loop
  int s = v;
#pragma unroll
  for (int off = 1; off < 64; off <<= 1) {
    int t = __shfl_up(s, off);
    if (lane >= off) s += t;
  }
  __shared__ int wsum[4];
  if (lane == 63) wsum[w] = s;
  __syncthreads();
  int add = 0;
#pragma unroll
  for (int i = 0; i < 4; ++i) add += (i < w) ? wsum[i] : 0;
  int incl = s + add;
  offs[idx] = incl - v;   // exclusive within block
  if (threadIdx.x == 255) bsum[blockIdx.x] = incl;
}

// ---------------- scan phase 2+3 fused: each block reduces bsum[0..bid) locally ----------------
__global__ __launch_bounds__(256) void scan3_kernel(const int* __restrict__ bsum,
                                                    int* __restrict__ offs,
                                                    int* __restrict__ nxt) {
  __shared__ int wsum[4];
  int tid = threadIdx.x, bid = blockIdx.x;
  int lane = tid & 63, w = tid >> 6;
  int v = (tid < bid) ? bsum[tid] : 0;   // bid<=124 so tid<bid => tid<125: in range
#pragma unroll
  for (int off = 1; off < 64; off <<= 1) v += __shfl_xor(v, off);
  if (lane == 0) wsum[w] = v;
  __syncthreads();
  int boff = wsum[0] + wsum[1] + wsum[2] + wsum[3];
  int idx = bid * 256 + tid;
  int o = offs[idx] + boff;
  offs[idx] = o;
  nxt[idx] = o;
  if (bid == 0 && tid == 0) offs[N_NODES] = EF_EDGES;   // grand total is static
}

// ---------------- CSR fill (includes self-loops, eid>=E) + inverse map ----------------
__global__ __launch_bounds__(256) void fill_kernel(const int* __restrict__ ei,
                                                   int* __restrict__ nxt,
                                                   int* __restrict__ csr_src,
                                                   int* __restrict__ csr_eid,
                                                   int* __restrict__ csr_pos) {
  int e = blockIdx.x * 256 + threadIdx.x;   // grid exactly EF/256
  int s, d;
  if (e < E_EDGES) { s = ei[e]; d = ei[E_EDGES + e]; }
  else             { s = e - E_EDGES; d = s; }
  int pos = atomicAdd(&nxt[d], 1);
  csr_src[pos] = s;
  csr_eid[pos] = e;
  csr_pos[e] = pos;
}

// ---------------- self-loop attr = mean of incoming edge_attr ----------------
__global__ __launch_bounds__(256) void loopattr_kernel(const int* __restrict__ offs,
                                                       const int* __restrict__ csr_eid,
                                                       const float* __restrict__ ea,
                                                       float* __restrict__ loop_attr) {
  int lane = threadIdx.x & 63;
  int n = blockIdx.x * 4 + (threadIdx.x >> 6);
  int k = lane & 15, g = lane >> 4;
  int beg = offs[n], end = offs[n + 1];
  float s = 0.f;
  for (int i = beg + g; i < end; i += 4) {
    int e = csr_eid[i];
    if (e < E_EDGES) s += ea[(size_t)e * 16 + k];
  }
  s += __shfl_xor(s, 16);
  s += __shfl_xor(s, 32);
  int degv = end - beg - 1;  // real in-edges
  if (g == 0) loop_attr[(size_t)n * 16 + k] = s / fmaxf((float)degv, 1.f);
}

// ---------------- edge logits, ALL 3 layers: lgE[l][pos][h] = (ea_f @ M_e[l]) fp16 ----------------
__global__ __launch_bounds__(256) void elogit_kernel(const float* __restrict__ edge_attr,
                                                     const float* __restrict__ loop_attr,
                                                     const float* __restrict__ W_e0,
                                                     const float* __restrict__ a_e0,
                                                     const float* __restrict__ W_eg,
                                                     const float* __restrict__ a_eg,
                                                     const int* __restrict__ csr_pos,
                                                     unsigned short* __restrict__ lgE) {
  __shared__ float sMe[3][16][4];
  int tid = threadIdx.x;
  if (tid < 192) {
    int l = tid >> 6, r6 = tid & 63, d = r6 >> 2, h = r6 & 3;
    const float* We = (l == 0) ? W_e0 : W_eg + (size_t)(l - 1) * 16 * HC;
    const float* ae = (l == 0) ? a_e0 : a_eg + (size_t)(l - 1) * 64;
    float s = 0.f;
#pragma unroll
    for (int c = 0; c < 16; ++c) s += We[d * HC + h * 16 + c] * ae[h * 16 + c];
    sMe[l][d][h] = s;
  }
  __syncthreads();
  int e = blockIdx.x * 256 + tid;   // grid exactly EF/256
  const float* ea = (e < E_EDGES) ? &edge_attr[(size_t)e * 16]
                                  : &loop_attr[(size_t)(e - E_EDGES) * 16];
  float av[16];
  *(float4*)&av[0]  = *(const float4*)(ea + 0);
  *(float4*)&av[4]  = *(const float4*)(ea + 4);
  *(float4*)&av[8]  = *(const float4*)(ea + 8);
  *(float4*)&av[12] = *(const float4*)(ea + 12);
  int pos = csr_pos[e];
#pragma unroll
  for (int l = 0; l < 3; ++l) {
    float r0 = 0.f, r1 = 0.f, r2 = 0.f, r3 = 0.f;
#pragma unroll
    for (int d = 0; d < 16; ++d) {
      float a = av[d];
      r0 = fmaf(a, sMe[l][d][0], r0);
      r1 = fmaf(a, sMe[l][d][1], r1);
      r2 = fmaf(a, sMe[l][d][2], r2);
      r3 = fmaf(a, sMe[l][d][3], r3);
    }
    unsigned long long u =
        (unsigned long long)f2h(r0) |
        ((unsigned long long)f2h(r1) << 16) |
        ((unsigned long long)f2h(r2) << 32) |
        ((unsigned long long)f2h(r3) << 48);
    __builtin_nontemporal_store(
        u, (unsigned long long*)&lgE[((size_t)l * EF_EDGES + pos) * 4]);
  }
}

// ---------------- xl(bf16) = A @ W ; fused al_s/al_d epilogue ----------------
template <int K>
__global__ __launch_bounds__(256) void transform_kernel(const float* __restrict__ A,
                                                        const float* __restrict__ W,
                                                        const float* __restrict__ a_s,
                                                        const float* __restrict__ a_d,
                                                        unsigned short* __restrict__ xlb,
                                                        float* __restrict__ al_s,
                                                        float* __restrict__ al_d) {
  __shared__ float sW[64][64];
  __shared__ float sA[64][65];
  int tid = threadIdx.x;
  int row0 = blockIdx.x * 64;
  int tx = tid & 15, ty = tid >> 4;
  int c0 = tx * 4, r0 = ty * 4;
  float acc[4][4] = {};
  for (int kc = 0; kc < K; kc += 64) {
    for (int i = tid; i < 1024; i += 256) {
      int kk = i >> 4, c4 = (i & 15) * 4;
      *(float4*)&sW[kk][c4] = *(const float4*)&W[(size_t)(kc + kk) * HC + c4];
    }
    for (int i = tid; i < 1024; i += 256) {
      int r = i >> 4, k4 = (i & 15) * 4;
      float4 v = *(const float4*)&A[(size_t)(row0 + r) * K + kc + k4];
      sA[r][k4 + 0] = v.x; sA[r][k4 + 1] = v.y;
      sA[r][k4 + 2] = v.z; sA[r][k4 + 3] = v.w;
    }
    __syncthreads();
#pragma unroll 8
    for (int kk = 0; kk < 64; ++kk) {
      float4 w = *(float4*)&sW[kk][c0];
      float a0 = sA[r0 + 0][kk];
      float a1 = sA[r0 + 1][kk];
      float a2 = sA[r0 + 2][kk];
      float a3 = sA[r0 + 3][kk];
      acc[0][0] = fmaf(a0, w.x, acc[0][0]); acc[0][1] = fmaf(a0, w.y, acc[0][1]);
      acc[0][2] = fmaf(a0, w.z, acc[0][2]); acc[0][3] = fmaf(a0, w.w, acc[0][3]);
      acc[1][0] = fmaf(a1, w.x, acc[1][0]); acc[1][1] = fmaf(a1, w.y, acc[1][1]);
      acc[1][2] = fmaf(a1, w.z, acc[1][2]); acc[1][3] = fmaf(a1, w.w, acc[1][3]);
      acc[2][0] = fmaf(a2, w.x, acc[2][0]); acc[2][1] = fmaf(a2, w.y, acc[2][1]);
      acc[2][2] = fmaf(a2, w.z, acc[2][2]); acc[2][3] = fmaf(a2, w.w, acc[2][3]);
      acc[3][0] = fmaf(a3, w.x, acc[3][0]); acc[3][1] = fmaf(a3, w.y, acc[3][1]);
      acc[3][2] = fmaf(a3, w.z, acc[3][2]); acc[3][3] = fmaf(a3, w.w, acc[3][3]);
    }
    __syncthreads();
  }
  float asv[4], adv[4];
#pragma unroll
  for (int j = 0; j < 4; ++j) { asv[j] = a_s[c0 + j]; adv[j] = a_d[c0 + j]; }
  int hd = tx >> 2;
#pragma unroll
  for (int i = 0; i < 4; ++i) {
    int r = row0 + r0 + i;
    ushort4 u = make_ushort4(f2bf(acc[i][0]), f2bf(acc[i][1]),
                             f2bf(acc[i][2]), f2bf(acc[i][3]));
    *(ushort4*)&xlb[(size_t)r * HC + c0] = u;
    float ps = acc[i][0] * asv[0] + acc[i][1] * asv[1] + acc[i][2] * asv[2] + acc[i][3] * asv[3];
    float pd = acc[i][0] * adv[0] + acc[i][1] * adv[1] + acc[i][2] * adv[2] + acc[i][3] * adv[3];
    ps += __shfl_xor(ps, 1); ps += __shfl_xor(ps, 2);
    pd += __shfl_xor(pd, 1); pd += __shfl_xor(pd, 2);
    if ((tx & 3) == 0) {
      al_s[(size_t)r * 4 + hd] = ps;
      al_d[(size_t)r * 4 + hd] = pd;
    }
  }
}

// ---------------- one-pass online softmax + aggregation (wave per node) ----------------
// streams (csr_src, lgE) loaded nontemporal so the 4MB xlb table stays L2-resident
template <int FUSE_PROJ>
__global__ __launch_bounds__(256) void gather_kernel(const int* __restrict__ offs,
                                                     const int* __restrict__ csr_src,
                                                     const unsigned short* __restrict__ lg,
                                                     const unsigned short* __restrict__ xlb,
                                                     const float* __restrict__ al_s,
                                                     const float* __restrict__ al_d,
                                                     const float* __restrict__ bias,
                                                     const float* __restrict__ Wp,
                                                     const float* __restrict__ bp,
                                                     float* __restrict__ outp) {
  int lane = threadIdx.x & 63;
  int n = blockIdx.x * 4 + (threadIdx.x >> 6);
  int hd = lane >> 4;
  int beg = offs[n], end = offs[n + 1];
  float ald = al_d[(size_t)n * 4 + hd];
  float m = -1e30f, denom = 0.f, acc = 0.f;
  int i = beg;
  for (; i + 4 <= end; i += 4) {
    int s0 = __builtin_nontemporal_load(&csr_src[i + 0]);
    int s1 = __builtin_nontemporal_load(&csr_src[i + 1]);
    int s2 = __builtin_nontemporal_load(&csr_src[i + 2]);
    int s3 = __builtin_nontemporal_load(&csr_src[i + 3]);
    unsigned short g0 = __builtin_nontemporal_load(&lg[(size_t)(i + 0) * 4 + hd]);
    unsigned short g1 = __builtin_nontemporal_load(&lg[(size_t)(i + 1) * 4 + hd]);
    unsigned short g2 = __builtin_nontemporal_load(&lg[(size_t)(i + 2) * 4 + hd]);
    unsigned short g3 = __builtin_nontemporal_load(&lg[(size_t)(i + 3) * 4 + hd]);
    float l0 = h2f(g0) + al_s[(size_t)s0 * 4 + hd] + ald;
    float l1 = h2f(g1) + al_s[(size_t)s1 * 4 + hd] + ald;
    float l2 = h2f(g2) + al_s[(size_t)s2 * 4 + hd] + ald;
    float l3 = h2f(g3) + al_s[(size_t)s3 * 4 + hd] + ald;
    l0 = (l0 > 0.f) ? l0 : 0.2f * l0;
    l1 = (l1 > 0.f) ? l1 : 0.2f * l1;
    l2 = (l2 > 0.f) ? l2 : 0.2f * l2;
    l3 = (l3 > 0.f) ? l3 : 0.2f * l3;
    unsigned short x0 = xlb[(size_t)s0 * HC + lane];
    unsigned short x1 = xlb[(size_t)s1 * HC + lane];
    unsigned short x2 = xlb[(size_t)s2 * HC + lane];
    unsigned short x3 = xlb[(size_t)s3 * HC + lane];
    float mx = fmaxf(fmaxf(fmaxf(l0, l1), fmaxf(l2, l3)), m);
    float sc = __expf(m - mx);
    float p0 = __expf(l0 - mx);
    float p1 = __expf(l1 - mx);
    float p2 = __expf(l2 - mx);
    float p3 = __expf(l3 - mx);
    denom = denom * sc + ((p0 + p1) + (p2 + p3));
    acc = acc * sc + p0 * bf2f(x0) + p1 * bf2f(x1) + p2 * bf2f(x2) + p3 * bf2f(x3);
    m = mx;
  }
  for (; i < end; ++i) {
    int s = __builtin_nontemporal_load(&csr_src[i]);
    unsigned short g = __builtin_nontemporal_load(&lg[(size_t)i * 4 + hd]);
    float l = h2f(g) + al_s[(size_t)s * 4 + hd] + ald;
    l = (l > 0.f) ? l : 0.2f * l;
    float mx = fmaxf(m, l);
    float sc = __expf(m - mx);
    float pp = __expf(l - mx);
    denom = denom * sc + pp;
    acc = acc * sc + pp * bf2f(xlb[(size_t)s * HC + lane]);
    m = mx;
  }
  float hv = fmaxf(acc / denom + bias[lane], 0.f);
  if constexpr (!FUSE_PROJ) {
    outp[(size_t)n * HC + lane] = hv;
  } else {
    float pj[8];
#pragma unroll
    for (int j = 0; j < 8; ++j) pj[j] = hv * Wp[lane * PROJ + j];
#pragma unroll
    for (int off = 1; off < 64; off <<= 1) {
#pragma unroll
      for (int j = 0; j < 8; ++j) pj[j] += __shfl_xor(pj[j], off);
    }
    if (lane < 8) {
      float v = pj[0];
      v = (lane == 1) ? pj[1] : v;
      v = (lane == 2) ? pj[2] : v;
      v = (lane == 3) ? pj[3] : v;
      v = (lane == 4) ? pj[4] : v;
      v = (lane == 5) ? pj[5] : v;
      v = (lane == 6) ? pj[6] : v;
      v = (lane == 7) ? pj[7] : v;
      outp[(size_t)n * PROJ + lane] = fmaxf(v + bp[lane], 0.f);
    }
  }
}

// ---------------- fc_out stage 1: K-chunked partials ----------------
__global__ __launch_bounds__(256) void fc1_kernel(const float* __restrict__ p,
                                                  const float* __restrict__ Wo,
                                                  float* __restrict__ part) {
  __shared__ float sp[NGRAPH][250];
  int kc = blockIdx.x;   // 0..31, chunk of 250 K
  int ct = blockIdx.y;   // 0..3, 64 cols
  int tid = threadIdx.x;
  for (int i = tid; i < NGRAPH * 250; i += 256) {
    int g = i / 250, kk = i % 250;
    sp[g][kk] = p[(size_t)g * 8000 + kc * 250 + kk];
  }
  __syncthreads();
  int c = ct * 64 + (tid & 63);
  int kg = tid >> 6;   // wave id, wave-uniform
  float acc[NGRAPH] = {};
  for (int kk = kg; kk < 250; kk += 4) {
    float w = __builtin_nontemporal_load(&Wo[(size_t)(kc * 250 + kk) * OUT_DIM + c]);
#pragma unroll
    for (int g = 0; g < NGRAPH; ++g) acc[g] = fmaf(sp[g][kk], w, acc[g]);
  }
  int ch = kc * 4 + kg;   // 0..127
#pragma unroll
  for (int g = 0; g < NGRAPH; ++g)
    part[((size_t)ch * NGRAPH + g) * OUT_DIM + c] = acc[g];
}

// ---------------- fc_out stage 2: reduce + bias ----------------
__global__ __launch_bounds__(256) void fc2_kernel(const float* __restrict__ part,
                                                  const float* __restrict__ bo,
                                                  float* __restrict__ out) {
  int i = blockIdx.x * 256 + threadIdx.x;   // 32*256 = 8192 exact
  int g = i >> 8, c = i & 255;
  float s = bo[c];
  for (int ch = 0; ch < 128; ++ch) s += part[((size_t)ch * NGRAPH + g) * OUT_DIM + c];
  out[i] = s;
}

extern "C" void kernel_launch(void* const* d_in, const int* in_sizes, int n_in,
                              void* d_out, int out_size, void* d_ws, size_t ws_size,
                              hipStream_t stream) {
  const float* x         = (const float*)d_in[0];
  const float* edge_attr = (const float*)d_in[1];
  const float* W0        = (const float*)d_in[2];
  const float* a_s0      = (const float*)d_in[3];
  const float* a_d0      = (const float*)d_in[4];
  const float* W_e0      = (const float*)d_in[5];
  const float* a_e0      = (const float*)d_in[6];
  const float* b0        = (const float*)d_in[7];
  const float* Wg        = (const float*)d_in[8];
  const float* a_sg      = (const float*)d_in[9];
  const float* a_dg      = (const float*)d_in[10];
  const float* W_eg      = (const float*)d_in[11];
  const float* a_eg      = (const float*)d_in[12];
  const float* bg        = (const float*)d_in[13];
  const float* Wp        = (const float*)d_in[14];
  const float* bp        = (const float*)d_in[15];
  const float* Wo        = (const float*)d_in[16];
  const float* bo        = (const float*)d_in[17];
  const int*   ei        = (const int*)d_in[18];

  char* base = (char*)d_ws;
  size_t off = 0;
  auto alloc = [&](size_t bytes) -> void* {
    void* ptr = base + off;
    off = (off + bytes + 255) & ~(size_t)255;
    return ptr;
  };
  int*            deg       = (int*)alloc((size_t)N_NODES * 4);
  int*            offs      = (int*)alloc((size_t)(N_NODES + 1) * 4);
  int*            nxt       = (int*)alloc((size_t)N_NODES * 4);
  int*            bsum      = (int*)alloc(128 * 4);
  int*            csr_src   = (int*)alloc((size_t)EF_EDGES * 4);
  int*            csr_eid   = (int*)alloc((size_t)EF_EDGES * 4);
  int*            csr_pos   = (int*)alloc((size_t)EF_EDGES * 4);
  float*          loop_attr = (float*)alloc((size_t)N_NODES * 16 * 4);
  unsigned short* lgE       = (unsigned short*)alloc((size_t)3 * EF_EDGES * 4 * 2);
  unsigned short* xlb       = (unsigned short*)alloc((size_t)N_NODES * HC * 2);
  float*          al_s      = (float*)alloc((size_t)N_NODES * 4 * 4);
  float*          al_d      = (float*)alloc((size_t)N_NODES * 4 * 4);
  float*          hA        = (float*)alloc((size_t)N_NODES * HC * 4);
  float*          hB        = (float*)alloc((size_t)N_NODES * HC * 4);
  float*          pbuf      = (float*)alloc((size_t)N_NODES * PROJ * 4);
  float*          part      = (float*)alloc((size_t)128 * NGRAPH * OUT_DIM * 4);

  // ---- graph preprocessing (dst is layer-invariant) ----
  zero_kernel<<<N_NODES / 256, 256, 0, stream>>>(deg);
  deg_kernel<<<E_EDGES / 256, 256, 0, stream>>>(ei, deg);
  scan1_kernel<<<N_NODES / 256, 256, 0, stream>>>(deg, offs, bsum);
  scan3_kernel<<<N_NODES / 256, 256, 0, stream>>>(bsum, offs, nxt);
  fill_kernel<<<EF_EDGES / 256, 256, 0, stream>>>(ei, nxt, csr_src, csr_eid, csr_pos);
  loopattr_kernel<<<N_NODES / 4, 256, 0, stream>>>(offs, csr_eid, edge_attr, loop_attr);
  elogit_kernel<<<EF_EDGES / 256, 256, 0, stream>>>(edge_attr, loop_attr, W_e0, a_e0,
                                                    W_eg, a_eg, csr_pos, lgE);

  // ---- layer 0: x(128) -> hA ----
  transform_kernel<FIN><<<N_NODES / 64, 256, 0, stream>>>(x, W0, a_s0, a_d0, xlb, al_s, al_d);
  gather_kernel<0><<<N_NODES / 4, 256, 0, stream>>>(offs, csr_src, lgE, xlb,
                                                    al_s, al_d, b0, Wp, bp, hA);

  // ---- layer 1: hA -> hB ----
  transform_kernel<HC><<<N_NODES / 64, 256, 0, stream>>>(hA, Wg, a_sg, a_dg, xlb, al_s, al_d);
  gather_kernel<0><<<N_NODES / 4, 256, 0, stream>>>(offs, csr_src, lgE + (size_t)EF_EDGES * 4,
                                                    xlb, al_s, al_d, bg, Wp, bp, hB);

  // ---- layer 2: hB -> pbuf (proj fused) ----
  transform_kernel<HC><<<N_NODES / 64, 256, 0, stream>>>(hB, Wg + HC * HC, a_sg + 64,
                                                         a_dg + 64, xlb, al_s, al_d);
  gather_kernel<1><<<N_NODES / 4, 256, 0, stream>>>(offs, csr_src, lgE + (size_t)2 * EF_EDGES * 4,
                                                    xlb, al_s, al_d, bg + 64, Wp, bp, pbuf);

  // ---- head ----
  fc1_kernel<<<dim3(32, 4), 256, 0, stream>>>(pbuf, Wo, part);
  fc2_kernel<<<NGRAPH, 256, 0, stream>>>(part, bo, (float*)d_out);
}

// Round 8
// 272.558 us; speedup vs baseline: 13.6207x; 1.1751x over previous
//
#include <hip/hip_runtime.h>
#include <hip/hip_bf16.h>
#include <hip/hip_fp16.h>

#define N_NODES 32000
#define FIN     128
#define E_EDGES 512000
#define EF_EDGES 544000
#define HC      64
#define NGRAPH  32
#define PROJ    8
#define OUT_DIM 256

// fp32 -> bf16 (RTNE) and back
static __device__ inline unsigned short f2bf(float f) {
  unsigned int x = __float_as_uint(f);
  unsigned int r = (x + 0x7fffu + ((x >> 16) & 1u)) >> 16;
  return (unsigned short)r;
}
static __device__ inline float bf2f(unsigned short u) {
  return __uint_as_float((unsigned int)u << 16);
}
// fp32 <-> fp16
static __device__ inline unsigned short f2h(float f) {
  return __half_as_ushort(__float2half(f));
}
static __device__ inline float h2f(unsigned short u) {
  return __half2float(__ushort_as_half(u));
}

// ---------------- zero deg ----------------
__global__ __launch_bounds__(256) void zero_kernel(int* __restrict__ deg) {
  deg[blockIdx.x * 256 + threadIdx.x] = 0;
}

// ---------------- degree count (int atomics) ----------------
__global__ __launch_bounds__(256) void deg_kernel(const int* __restrict__ ei,
                                                  int* __restrict__ deg) {
  int e = blockIdx.x * 256 + threadIdx.x;   // grid exactly E/256
  atomicAdd(&deg[ei[E_EDGES + e]], 1);
}

// ---------------- scan phase 1: per-block exclusive scan + block sums ----------------
__global__ __launch_bounds__(256) void scan1_kernel(const int* __restrict__ deg,
                                                    int* __restrict__ offs,
                                                    int* __restrict__ bsum) {
  int idx = blockIdx.x * 256 + threadIdx.x;   // grid exactly 125
  int lane = threadIdx.x & 63;
  int w = threadIdx.x >> 6;
  int v = deg[idx] + 1;   // +1 self-loop
  int s = v;
#pragma unroll
  for (int off = 1; off < 64; off <<= 1) {
    int t = __shfl_up(s, off);
    if (lane >= off) s += t;
  }
  __shared__ int wsum[4];
  if (lane == 63) wsum[w] = s;
  __syncthreads();
  int add = 0;
#pragma unroll
  for (int i = 0; i < 4; ++i) add += (i < w) ? wsum[i] : 0;
  int incl = s + add;
  offs[idx] = incl - v;   // exclusive within block
  if (threadIdx.x == 255) bsum[blockIdx.x] = incl;
}

// ---------------- scan phase 2+3 fused: each block reduces bsum[0..bid) locally ----------------
__global__ __launch_bounds__(256) void scan3_kernel(const int* __restrict__ bsum,
                                                    int* __restrict__ offs,
                                                    int* __restrict__ nxt) {
  __shared__ int wsum[4];
  int tid = threadIdx.x, bid = blockIdx.x;
  int lane = tid & 63, w = tid >> 6;
  int v = (tid < bid) ? bsum[tid] : 0;   // bid<=124 so tid<bid => tid<125: in range
#pragma unroll
  for (int off = 1; off < 64; off <<= 1) v += __shfl_xor(v, off);
  if (lane == 0) wsum[w] = v;
  __syncthreads();
  int boff = wsum[0] + wsum[1] + wsum[2] + wsum[3];
  int idx = bid * 256 + tid;
  int o = offs[idx] + boff;
  offs[idx] = o;
  nxt[idx] = o;
  if (bid == 0 && tid == 0) offs[N_NODES] = EF_EDGES;   // grand total is static
}

// ---------------- CSR fill (includes self-loops, eid>=E) ----------------
__global__ __launch_bounds__(256) void fill_kernel(const int* __restrict__ ei,
                                                   int* __restrict__ nxt,
                                                   int* __restrict__ csr_src,
                                                   int* __restrict__ csr_eid) {
  int e = blockIdx.x * 256 + threadIdx.x;   // grid exactly EF/256
  int s, d;
  if (e < E_EDGES) { s = ei[e]; d = ei[E_EDGES + e]; }
  else             { s = e - E_EDGES; d = s; }
  int pos = atomicAdd(&nxt[d], 1);
  csr_src[pos] = s;
  csr_eid[pos] = e;
}

// ---------------- self-loop attr = mean of incoming edge_attr ----------------
__global__ __launch_bounds__(256) void loopattr_kernel(const int* __restrict__ offs,
                                                       const int* __restrict__ csr_eid,
                                                       const float* __restrict__ ea,
                                                       float* __restrict__ loop_attr) {
  int lane = threadIdx.x & 63;
  int n = blockIdx.x * 4 + (threadIdx.x >> 6);
  int k = lane & 15, g = lane >> 4;
  int beg = offs[n], end = offs[n + 1];
  float s = 0.f;
  for (int i = beg + g; i < end; i += 4) {
    int e = csr_eid[i];
    if (e < E_EDGES) s += ea[(size_t)e * 16 + k];
  }
  s += __shfl_xor(s, 16);
  s += __shfl_xor(s, 32);
  int degv = end - beg - 1;  // real in-edges
  if (g == 0) loop_attr[(size_t)n * 16 + k] = s / fmaxf((float)degv, 1.f);
}

// ---------------- edge logits, ALL 3 layers, CSR-pos order ----------------
// gather-direction: coalesced lgE writes; random full-line edge_attr reads (L3-hit)
__global__ __launch_bounds__(256) void elogit_kernel(const float* __restrict__ edge_attr,
                                                     const float* __restrict__ loop_attr,
                                                     const float* __restrict__ W_e0,
                                                     const float* __restrict__ a_e0,
                                                     const float* __restrict__ W_eg,
                                                     const float* __restrict__ a_eg,
                                                     const int* __restrict__ csr_eid,
                                                     unsigned short* __restrict__ lgE) {
  __shared__ float sMe[3][16][4];
  int tid = threadIdx.x;
  if (tid < 192) {
    int l = tid >> 6, r6 = tid & 63, d = r6 >> 2, h = r6 & 3;
    const float* We = (l == 0) ? W_e0 : W_eg + (size_t)(l - 1) * 16 * HC;
    const float* ae = (l == 0) ? a_e0 : a_eg + (size_t)(l - 1) * 64;
    float s = 0.f;
#pragma unroll
    for (int c = 0; c < 16; ++c) s += We[d * HC + h * 16 + c] * ae[h * 16 + c];
    sMe[l][d][h] = s;
  }
  __syncthreads();
  int pos = blockIdx.x * 256 + tid;   // grid exactly EF/256
  int e = csr_eid[pos];
  const float* ea = (e < E_EDGES) ? &edge_attr[(size_t)e * 16]
                                  : &loop_attr[(size_t)(e - E_EDGES) * 16];
  float av[16];
  *(float4*)&av[0]  = *(const float4*)(ea + 0);
  *(float4*)&av[4]  = *(const float4*)(ea + 4);
  *(float4*)&av[8]  = *(const float4*)(ea + 8);
  *(float4*)&av[12] = *(const float4*)(ea + 12);
#pragma unroll
  for (int l = 0; l < 3; ++l) {
    float r0 = 0.f, r1 = 0.f, r2 = 0.f, r3 = 0.f;
#pragma unroll
    for (int d = 0; d < 16; ++d) {
      float a = av[d];
      r0 = fmaf(a, sMe[l][d][0], r0);
      r1 = fmaf(a, sMe[l][d][1], r1);
      r2 = fmaf(a, sMe[l][d][2], r2);
      r3 = fmaf(a, sMe[l][d][3], r3);
    }
    unsigned long long u =
        (unsigned long long)f2h(r0) |
        ((unsigned long long)f2h(r1) << 16) |
        ((unsigned long long)f2h(r2) << 32) |
        ((unsigned long long)f2h(r3) << 48);
    __builtin_nontemporal_store(
        u, (unsigned long long*)&lgE[((size_t)l * EF_EDGES + pos) * 4]);
  }
}

// ---------------- xl(bf16) = A @ W ; fused al_s/al_d epilogue ----------------
template <int K>
__global__ __launch_bounds__(256) void transform_kernel(const float* __restrict__ A,
                                                        const float* __restrict__ W,
                                                        const float* __restrict__ a_s,
                                                        const float* __restrict__ a_d,
                                                        unsigned short* __restrict__ xlb,
                                                        float* __restrict__ al_s,
                                                        float* __restrict__ al_d) {
  __shared__ float sW[64][64];
  __shared__ float sA[64][65];
  int tid = threadIdx.x;
  int row0 = blockIdx.x * 64;
  int tx = tid & 15, ty = tid >> 4;
  int c0 = tx * 4, r0 = ty * 4;
  float acc[4][4] = {};
  for (int kc = 0; kc < K; kc += 64) {
    for (int i = tid; i < 1024; i += 256) {
      int kk = i >> 4, c4 = (i & 15) * 4;
      *(float4*)&sW[kk][c4] = *(const float4*)&W[(size_t)(kc + kk) * HC + c4];
    }
    for (int i = tid; i < 1024; i += 256) {
      int r = i >> 4, k4 = (i & 15) * 4;
      float4 v = *(const float4*)&A[(size_t)(row0 + r) * K + kc + k4];
      sA[r][k4 + 0] = v.x; sA[r][k4 + 1] = v.y;
      sA[r][k4 + 2] = v.z; sA[r][k4 + 3] = v.w;
    }
    __syncthreads();
#pragma unroll 8
    for (int kk = 0; kk < 64; ++kk) {
      float4 w = *(float4*)&sW[kk][c0];
      float a0 = sA[r0 + 0][kk];
      float a1 = sA[r0 + 1][kk];
      float a2 = sA[r0 + 2][kk];
      float a3 = sA[r0 + 3][kk];
      acc[0][0] = fmaf(a0, w.x, acc[0][0]); acc[0][1] = fmaf(a0, w.y, acc[0][1]);
      acc[0][2] = fmaf(a0, w.z, acc[0][2]); acc[0][3] = fmaf(a0, w.w, acc[0][3]);
      acc[1][0] = fmaf(a1, w.x, acc[1][0]); acc[1][1] = fmaf(a1, w.y, acc[1][1]);
      acc[1][2] = fmaf(a1, w.z, acc[1][2]); acc[1][3] = fmaf(a1, w.w, acc[1][3]);
      acc[2][0] = fmaf(a2, w.x, acc[2][0]); acc[2][1] = fmaf(a2, w.y, acc[2][1]);
      acc[2][2] = fmaf(a2, w.z, acc[2][2]); acc[2][3] = fmaf(a2, w.w, acc[2][3]);
      acc[3][0] = fmaf(a3, w.x, acc[3][0]); acc[3][1] = fmaf(a3, w.y, acc[3][1]);
      acc[3][2] = fmaf(a3, w.z, acc[3][2]); acc[3][3] = fmaf(a3, w.w, acc[3][3]);
    }
    __syncthreads();
  }
  float asv[4], adv[4];
#pragma unroll
  for (int j = 0; j < 4; ++j) { asv[j] = a_s[c0 + j]; adv[j] = a_d[c0 + j]; }
  int hd = tx >> 2;
#pragma unroll
  for (int i = 0; i < 4; ++i) {
    int r = row0 + r0 + i;
    ushort4 u = make_ushort4(f2bf(acc[i][0]), f2bf(acc[i][1]),
                             f2bf(acc[i][2]), f2bf(acc[i][3]));
    *(ushort4*)&xlb[(size_t)r * HC + c0] = u;
    float ps = acc[i][0] * asv[0] + acc[i][1] * asv[1] + acc[i][2] * asv[2] + acc[i][3] * asv[3];
    float pd = acc[i][0] * adv[0] + acc[i][1] * adv[1] + acc[i][2] * adv[2] + acc[i][3] * adv[3];
    ps += __shfl_xor(ps, 1); ps += __shfl_xor(ps, 2);
    pd += __shfl_xor(pd, 1); pd += __shfl_xor(pd, 2);
    if ((tx & 3) == 0) {
      al_s[(size_t)r * 4 + hd] = ps;
      al_d[(size_t)r * 4 + hd] = pd;
    }
  }
}

// ---------------- one-pass online softmax + aggregation (wave per node) ----------------
template <int FUSE_PROJ>
__global__ __launch_bounds__(256) void gather_kernel(const int* __restrict__ offs,
                                                     const int* __restrict__ csr_src,
                                                     const unsigned short* __restrict__ lg,
                                                     const unsigned short* __restrict__ xlb,
                                                     const float* __restrict__ al_s,
                                                     const float* __restrict__ al_d,
                                                     const float* __restrict__ bias,
                                                     const float* __restrict__ Wp,
                                                     const float* __restrict__ bp,
                                                     float* __restrict__ outp) {
  int lane = threadIdx.x & 63;
  int n = blockIdx.x * 4 + (threadIdx.x >> 6);
  int hd = lane >> 4;
  int beg = offs[n], end = offs[n + 1];
  float ald = al_d[(size_t)n * 4 + hd];
  float m = -1e30f, denom = 0.f, acc = 0.f;
  int i = beg;
  for (; i + 4 <= end; i += 4) {
    int s0 = csr_src[i + 0];
    int s1 = csr_src[i + 1];
    int s2 = csr_src[i + 2];
    int s3 = csr_src[i + 3];
    unsigned short g0 = lg[(size_t)(i + 0) * 4 + hd];
    unsigned short g1 = lg[(size_t)(i + 1) * 4 + hd];
    unsigned short g2 = lg[(size_t)(i + 2) * 4 + hd];
    unsigned short g3 = lg[(size_t)(i + 3) * 4 + hd];
    float l0 = h2f(g0) + al_s[(size_t)s0 * 4 + hd] + ald;
    float l1 = h2f(g1) + al_s[(size_t)s1 * 4 + hd] + ald;
    float l2 = h2f(g2) + al_s[(size_t)s2 * 4 + hd] + ald;
    float l3 = h2f(g3) + al_s[(size_t)s3 * 4 + hd] + ald;
    l0 = (l0 > 0.f) ? l0 : 0.2f * l0;
    l1 = (l1 > 0.f) ? l1 : 0.2f * l1;
    l2 = (l2 > 0.f) ? l2 : 0.2f * l2;
    l3 = (l3 > 0.f) ? l3 : 0.2f * l3;
    unsigned short x0 = xlb[(size_t)s0 * HC + lane];
    unsigned short x1 = xlb[(size_t)s1 * HC + lane];
    unsigned short x2 = xlb[(size_t)s2 * HC + lane];
    unsigned short x3 = xlb[(size_t)s3 * HC + lane];
    float mx = fmaxf(fmaxf(fmaxf(l0, l1), fmaxf(l2, l3)), m);
    float sc = __expf(m - mx);
    float p0 = __expf(l0 - mx);
    float p1 = __expf(l1 - mx);
    float p2 = __expf(l2 - mx);
    float p3 = __expf(l3 - mx);
    denom = denom * sc + ((p0 + p1) + (p2 + p3));
    acc = acc * sc + p0 * bf2f(x0) + p1 * bf2f(x1) + p2 * bf2f(x2) + p3 * bf2f(x3);
    m = mx;
  }
  for (; i < end; ++i) {
    int s = csr_src[i];
    unsigned short g = lg[(size_t)i * 4 + hd];
    float l = h2f(g) + al_s[(size_t)s * 4 + hd] + ald;
    l = (l > 0.f) ? l : 0.2f * l;
    float mx = fmaxf(m, l);
    float sc = __expf(m - mx);
    float pp = __expf(l - mx);
    denom = denom * sc + pp;
    acc = acc * sc + pp * bf2f(xlb[(size_t)s * HC + lane]);
    m = mx;
  }
  float hv = fmaxf(acc / denom + bias[lane], 0.f);
  if constexpr (!FUSE_PROJ) {
    outp[(size_t)n * HC + lane] = hv;
  } else {
    float pj[8];
#pragma unroll
    for (int j = 0; j < 8; ++j) pj[j] = hv * Wp[lane * PROJ + j];
#pragma unroll
    for (int off = 1; off < 64; off <<= 1) {
#pragma unroll
      for (int j = 0; j < 8; ++j) pj[j] += __shfl_xor(pj[j], off);
    }
    if (lane < 8) {
      float v = pj[0];
      v = (lane == 1) ? pj[1] : v;
      v = (lane == 2) ? pj[2] : v;
      v = (lane == 3) ? pj[3] : v;
      v = (lane == 4) ? pj[4] : v;
      v = (lane == 5) ? pj[5] : v;
      v = (lane == 6) ? pj[6] : v;
      v = (lane == 7) ? pj[7] : v;
      outp[(size_t)n * PROJ + lane] = fmaxf(v + bp[lane], 0.f);
    }
  }
}

// ---------------- fc_out stage 1: K-chunked partials ----------------
__global__ __launch_bounds__(256) void fc1_kernel(const float* __restrict__ p,
                                                  const float* __restrict__ Wo,
                                                  float* __restrict__ part) {
  __shared__ float sp[NGRAPH][250];
  int kc = blockIdx.x;   // 0..31, chunk of 250 K
  int ct = blockIdx.y;   // 0..3, 64 cols
  int tid = threadIdx.x;
  for (int i = tid; i < NGRAPH * 250; i += 256) {
    int g = i / 250, kk = i % 250;
    sp[g][kk] = p[(size_t)g * 8000 + kc * 250 + kk];
  }
  __syncthreads();
  int c = ct * 64 + (tid & 63);
  int kg = tid >> 6;   // wave id, wave-uniform
  float acc[NGRAPH] = {};
  for (int kk = kg; kk < 250; kk += 4) {
    float w = __builtin_nontemporal_load(&Wo[(size_t)(kc * 250 + kk) * OUT_DIM + c]);
#pragma unroll
    for (int g = 0; g < NGRAPH; ++g) acc[g] = fmaf(sp[g][kk], w, acc[g]);
  }
  int ch = kc * 4 + kg;   // 0..127
#pragma unroll
  for (int g = 0; g < NGRAPH; ++g)
    part[((size_t)ch * NGRAPH + g) * OUT_DIM + c] = acc[g];
}

// ---------------- fc_out stage 2: reduce + bias ----------------
__global__ __launch_bounds__(256) void fc2_kernel(const float* __restrict__ part,
                                                  const float* __restrict__ bo,
                                                  float* __restrict__ out) {
  int i = blockIdx.x * 256 + threadIdx.x;   // 32*256 = 8192 exact
  int g = i >> 8, c = i & 255;
  float s = bo[c];
  for (int ch = 0; ch < 128; ++ch) s += part[((size_t)ch * NGRAPH + g) * OUT_DIM + c];
  out[i] = s;
}

extern "C" void kernel_launch(void* const* d_in, const int* in_sizes, int n_in,
                              void* d_out, int out_size, void* d_ws, size_t ws_size,
                              hipStream_t stream) {
  const float* x         = (const float*)d_in[0];
  const float* edge_attr = (const float*)d_in[1];
  const float* W0        = (const float*)d_in[2];
  const float* a_s0      = (const float*)d_in[3];
  const float* a_d0      = (const float*)d_in[4];
  const float* W_e0      = (const float*)d_in[5];
  const float* a_e0      = (const float*)d_in[6];
  const float* b0        = (const float*)d_in[7];
  const float* Wg        = (const float*)d_in[8];
  const float* a_sg      = (const float*)d_in[9];
  const float* a_dg      = (const float*)d_in[10];
  const float* W_eg      = (const float*)d_in[11];
  const float* a_eg      = (const float*)d_in[12];
  const float* bg        = (const float*)d_in[13];
  const float* Wp        = (const float*)d_in[14];
  const float* bp        = (const float*)d_in[15];
  const float* Wo        = (const float*)d_in[16];
  const float* bo        = (const float*)d_in[17];
  const int*   ei        = (const int*)d_in[18];

  char* base = (char*)d_ws;
  size_t off = 0;
  auto alloc = [&](size_t bytes) -> void* {
    void* ptr = base + off;
    off = (off + bytes + 255) & ~(size_t)255;
    return ptr;
  };
  int*            deg       = (int*)alloc((size_t)N_NODES * 4);
  int*            offs      = (int*)alloc((size_t)(N_NODES + 1) * 4);
  int*            nxt       = (int*)alloc((size_t)N_NODES * 4);
  int*            bsum      = (int*)alloc(128 * 4);
  int*            csr_src   = (int*)alloc((size_t)EF_EDGES * 4);
  int*            csr_eid   = (int*)alloc((size_t)EF_EDGES * 4);
  float*          loop_attr = (float*)alloc((size_t)N_NODES * 16 * 4);
  unsigned short* lgE       = (unsigned short*)alloc((size_t)3 * EF_EDGES * 4 * 2);
  unsigned short* xlb       = (unsigned short*)alloc((size_t)N_NODES * HC * 2);
  float*          al_s      = (float*)alloc((size_t)N_NODES * 4 * 4);
  float*          al_d      = (float*)alloc((size_t)N_NODES * 4 * 4);
  float*          hA        = (float*)alloc((size_t)N_NODES * HC * 4);
  float*          hB        = (float*)alloc((size_t)N_NODES * HC * 4);
  float*          pbuf      = (float*)alloc((size_t)N_NODES * PROJ * 4);
  float*          part      = (float*)alloc((size_t)128 * NGRAPH * OUT_DIM * 4);

  // ---- graph preprocessing (dst is layer-invariant) ----
  zero_kernel<<<N_NODES / 256, 256, 0, stream>>>(deg);
  deg_kernel<<<E_EDGES / 256, 256, 0, stream>>>(ei, deg);
  scan1_kernel<<<N_NODES / 256, 256, 0, stream>>>(deg, offs, bsum);
  scan3_kernel<<<N_NODES / 256, 256, 0, stream>>>(bsum, offs, nxt);
  fill_kernel<<<EF_EDGES / 256, 256, 0, stream>>>(ei, nxt, csr_src, csr_eid);
  loopattr_kernel<<<N_NODES / 4, 256, 0, stream>>>(offs, csr_eid, edge_attr, loop_attr);
  elogit_kernel<<<EF_EDGES / 256, 256, 0, stream>>>(edge_attr, loop_attr, W_e0, a_e0,
                                                    W_eg, a_eg, csr_eid, lgE);

  // ---- layer 0: x(128) -> hA ----
  transform_kernel<FIN><<<N_NODES / 64, 256, 0, stream>>>(x, W0, a_s0, a_d0, xlb, al_s, al_d);
  gather_kernel<0><<<N_NODES / 4, 256, 0, stream>>>(offs, csr_src, lgE, xlb,
                                                    al_s, al_d, b0, Wp, bp, hA);

  // ---- layer 1: hA -> hB ----
  transform_kernel<HC><<<N_NODES / 64, 256, 0, stream>>>(hA, Wg, a_sg, a_dg, xlb, al_s, al_d);
  gather_kernel<0><<<N_NODES / 4, 256, 0, stream>>>(offs, csr_src, lgE + (size_t)EF_EDGES * 4,
                                                    xlb, al_s, al_d, bg, Wp, bp, hB);

  // ---- layer 2: hB -> pbuf (proj fused) ----
  transform_kernel<HC><<<N_NODES / 64, 256, 0, stream>>>(hB, Wg + HC * HC, a_sg + 64,
                                                         a_dg + 64, xlb, al_s, al_d);
  gather_kernel<1><<<N_NODES / 4, 256, 0, stream>>>(offs, csr_src, lgE + (size_t)2 * EF_EDGES * 4,
                                                    xlb, al_s, al_d, bg + 64, Wp, bp, pbuf);

  // ---- head ----
  fc1_kernel<<<dim3(32, 4), 256, 0, stream>>>(pbuf, Wo, part);
  fc2_kernel<<<NGRAPH, 256, 0, stream>>>(part, bo, (float*)d_out);
}